// Round 1
// 2074.617 us; speedup vs baseline: 1.2289x; 1.2289x over previous
//
#include <hip/hip_runtime.h>
#include <math.h>

#define Nn    100000
#define Ee    3200000
#define NNZn  6400000
#define NF    (Nn * 16)     // floats per node-feature buffer
#define SCAN_NB 98          // ceil(Nn / 1024)

// ---------------------------------------------------------------------------
// Exact per-row histogram via global atomics (keys uniform over Nn -> low
// contention). int4-vectorized key loads.
// ---------------------------------------------------------------------------
__global__ __launch_bounds__(256) void hist_kernel(
    const int* __restrict__ keys, int n, int* __restrict__ cnt) {
  int i = (blockIdx.x * 256 + threadIdx.x) * 4;
  if (i + 3 < n) {
    int4 k = *(const int4*)(keys + i);
    atomicAdd(&cnt[k.x], 1);
    atomicAdd(&cnt[k.y], 1);
    atomicAdd(&cnt[k.z], 1);
    atomicAdd(&cnt[k.w], 1);
  } else {
    for (; i < n; ++i) atomicAdd(&cnt[keys[i]], 1);
  }
}

// ---------------------------------------------------------------------------
// 3-phase exclusive scan over Nn counts (x2 arrays via blockIdx.y).
// Phase 1: per-block inclusive scan -> inc (stored in cur), block sums.
// ---------------------------------------------------------------------------
__global__ __launch_bounds__(1024) void scan_local(
    const int* __restrict__ cnt_e, const int* __restrict__ cnt_p,
    int* __restrict__ inc_e, int* __restrict__ inc_p, int* __restrict__ bsum) {
  const int* cnt = blockIdx.y ? cnt_p : cnt_e;
  int* inc = blockIdx.y ? inc_p : inc_e;
  __shared__ int s[1024];
  int t = threadIdx.x;
  int i = blockIdx.x * 1024 + t;
  int v = (i < Nn) ? cnt[i] : 0;
  s[t] = v;
  __syncthreads();
  for (int off = 1; off < 1024; off <<= 1) {
    int u = (t >= off) ? s[t - off] : 0;
    __syncthreads();
    s[t] += u;
    __syncthreads();
  }
  if (i < Nn) inc[i] = s[t];
  if (t == 1023) bsum[blockIdx.y * SCAN_NB + blockIdx.x] = s[t];
}

// Phase 2: scan the SCAN_NB block sums (in place, -> exclusive). 2 blocks.
__global__ __launch_bounds__(128) void scan_bsum(int* __restrict__ bsum) {
  __shared__ int s[128];
  int t = threadIdx.x;
  int v = (t < SCAN_NB) ? bsum[blockIdx.x * SCAN_NB + t] : 0;
  s[t] = v;
  __syncthreads();
  for (int off = 1; off < 128; off <<= 1) {
    int u = (t >= off) ? s[t - off] : 0;
    __syncthreads();
    s[t] += u;
    __syncthreads();
  }
  if (t < SCAN_NB) bsum[blockIdx.x * SCAN_NB + t] = s[t] - v;  // exclusive
}

// Phase 3: finalize row_ptr (exclusive, Nn+1) and scatter cursors.
__global__ __launch_bounds__(1024) void scan_fix(
    const int* __restrict__ cnt_e, const int* __restrict__ cnt_p,
    int* __restrict__ cur_e, int* __restrict__ cur_p,  // holds inclusive scan
    int* __restrict__ rp_e, int* __restrict__ rp_p,
    const int* __restrict__ bsum) {
  const int* cnt = blockIdx.y ? cnt_p : cnt_e;
  int* cur = blockIdx.y ? cur_p : cur_e;
  int* rp  = blockIdx.y ? rp_p  : rp_e;
  int i = blockIdx.x * 1024 + threadIdx.x;
  if (i >= Nn) return;
  int incl = cur[i] + bsum[blockIdx.y * SCAN_NB + blockIdx.x];
  rp[i + 1] = incl;
  cur[i] = incl - cnt[i];    // exclusive start = scatter cursor
  if (i == 0) rp[0] = 0;
}

// ---------------------------------------------------------------------------
// Scatter into row-sorted CSR order.
// ---------------------------------------------------------------------------
__global__ __launch_bounds__(256) void bin_edges_csr(
    const int* __restrict__ dst, const int* __restrict__ src,
    int* __restrict__ cur, int* __restrict__ out) {
  int i = (blockIdx.x * 256 + threadIdx.x) * 4;
  if (i >= Ee) return;
  int4 d = *(const int4*)(dst + i);
  int4 s = *(const int4*)(src + i);
  out[atomicAdd(&cur[d.x], 1)] = s.x;
  out[atomicAdd(&cur[d.y], 1)] = s.y;
  out[atomicAdd(&cur[d.z], 1)] = s.z;
  out[atomicAdd(&cur[d.w], 1)] = s.w;
}

__global__ __launch_bounds__(256) void bin_pm_csr(
    const int* __restrict__ rows, const int* __restrict__ cols,
    const float* __restrict__ vals,
    int* __restrict__ cur, int2* __restrict__ out) {
  int i = (blockIdx.x * 256 + threadIdx.x) * 4;
  if (i >= NNZn) return;
  int4 r = *(const int4*)(rows + i);
  int4 c = *(const int4*)(cols + i);
  float4 v = *(const float4*)(vals + i);
  out[atomicAdd(&cur[r.x], 1)] = make_int2(c.x, __float_as_int(v.x));
  out[atomicAdd(&cur[r.y], 1)] = make_int2(c.y, __float_as_int(v.y));
  out[atomicAdd(&cur[r.z], 1)] = make_int2(c.z, __float_as_int(v.z));
  out[atomicAdd(&cur[r.w], 1)] = make_int2(c.w, __float_as_int(v.w));
}

// ---------------------------------------------------------------------------
// CSR hop: one 16-lane group per row, register accumulation, unroll x8.
// No LDS, no atomics, no barriers; 8 gathers in flight per group.
// ---------------------------------------------------------------------------
__global__ __launch_bounds__(256) void hop_csr(
    const float* __restrict__ zin, float* __restrict__ zout,
    const int* __restrict__ cs, const int* __restrict__ rp) {
  int gid = (blockIdx.x * 256 + threadIdx.x) >> 4;
  int f = threadIdx.x & 15;
  if (gid >= Nn) return;
  int j = rp[gid], e = rp[gid + 1];
  float a = 0.f;
  for (; j + 8 <= e; j += 8) {
    int s0 = cs[j],     s1 = cs[j + 1], s2 = cs[j + 2], s3 = cs[j + 3];
    int s4 = cs[j + 4], s5 = cs[j + 5], s6 = cs[j + 6], s7 = cs[j + 7];
    float x0 = zin[(size_t)s0 * 16 + f];
    float x1 = zin[(size_t)s1 * 16 + f];
    float x2 = zin[(size_t)s2 * 16 + f];
    float x3 = zin[(size_t)s3 * 16 + f];
    float x4 = zin[(size_t)s4 * 16 + f];
    float x5 = zin[(size_t)s5 * 16 + f];
    float x6 = zin[(size_t)s6 * 16 + f];
    float x7 = zin[(size_t)s7 * 16 + f];
    a += ((x0 + x1) + (x2 + x3)) + ((x4 + x5) + (x6 + x7));
  }
  for (; j < e; ++j) a += zin[(size_t)cs[j] * 16 + f];
  zout[(size_t)gid * 16 + f] = a;
}

// ---------------------------------------------------------------------------
// CSR pm: same structure, val * feat_b[col].
// ---------------------------------------------------------------------------
__global__ __launch_bounds__(256) void pm_csr(
    const float* __restrict__ fb, const int2* __restrict__ bp,
    const int* __restrict__ rp, float* __restrict__ pmy) {
  int gid = (blockIdx.x * 256 + threadIdx.x) >> 4;
  int f = threadIdx.x & 15;
  if (gid >= Nn) return;
  int j = rp[gid], e = rp[gid + 1];
  float a = 0.f;
  for (; j + 8 <= e; j += 8) {
    int2 e0 = bp[j],     e1 = bp[j + 1], e2 = bp[j + 2], e3 = bp[j + 3];
    int2 e4 = bp[j + 4], e5 = bp[j + 5], e6 = bp[j + 6], e7 = bp[j + 7];
    float x0 = fb[(size_t)e0.x * 16 + f];
    float x1 = fb[(size_t)e1.x * 16 + f];
    float x2 = fb[(size_t)e2.x * 16 + f];
    float x3 = fb[(size_t)e3.x * 16 + f];
    float x4 = fb[(size_t)e4.x * 16 + f];
    float x5 = fb[(size_t)e5.x * 16 + f];
    float x6 = fb[(size_t)e6.x * 16 + f];
    float x7 = fb[(size_t)e7.x * 16 + f];
    a += __int_as_float(e0.y) * x0 + __int_as_float(e1.y) * x1;
    a += __int_as_float(e2.y) * x2 + __int_as_float(e3.y) * x3;
    a += __int_as_float(e4.y) * x4 + __int_as_float(e5.y) * x5;
    a += __int_as_float(e6.y) * x6 + __int_as_float(e7.y) * x7;
  }
  for (; j < e; ++j) {
    int2 ee = bp[j];
    a += __int_as_float(ee.y) * fb[(size_t)ee.x * 16 + f];
  }
  pmy[(size_t)gid * 16 + f] = a;
}

// ---------------------------------------------------------------------------
// Fused per-node projections + ReLU(second half) + BN-stat partial reduction.
// (unchanged from previous verified version)
// ---------------------------------------------------------------------------
__global__ __launch_bounds__(256) void fuse_kernel(
    const float* __restrict__ feat_a, const float* __restrict__ deg,
    const float* __restrict__ z1, const float* __restrict__ z2,
    const float* __restrict__ z4, const float* __restrict__ pmy,
    const float* __restrict__ Wprev, const float* __restrict__ bprev,
    const float* __restrict__ Wdeg,  const float* __restrict__ bdeg,
    const float* __restrict__ Wrad,  const float* __restrict__ brad,
    const float* __restrict__ Wfuse, const float* __restrict__ bfuse,
    float* __restrict__ result, float* __restrict__ stats) {
  __shared__ float sWp[256], sWd[256], sWr[768], sWf[256], sB[16];
  int t = threadIdx.x;
  sWp[t] = Wprev[t];
  sWd[t] = Wdeg[t];
  sWf[t] = Wfuse[t];
  for (int i = t; i < 768; i += 256) sWr[i] = Wrad[i];
  if (t < 16)
    sB[t] = bprev[t] + bdeg[t] + brad[t] + brad[16 + t] + brad[32 + t] + bfuse[t];
  __syncthreads();

  int n = blockIdx.x * 256 + t;
  bool valid = n < Nn;

  float fa[16], a1[16], a2[16], a4[16], py[16];
  float dg = 0.f;
  if (valid) {
    const float4* p;
    p = (const float4*)(feat_a + (size_t)n * 16);
    ((float4*)fa)[0] = p[0]; ((float4*)fa)[1] = p[1];
    ((float4*)fa)[2] = p[2]; ((float4*)fa)[3] = p[3];
    p = (const float4*)(z1 + (size_t)n * 16);
    ((float4*)a1)[0] = p[0]; ((float4*)a1)[1] = p[1];
    ((float4*)a1)[2] = p[2]; ((float4*)a1)[3] = p[3];
    p = (const float4*)(z2 + (size_t)n * 16);
    ((float4*)a2)[0] = p[0]; ((float4*)a2)[1] = p[1];
    ((float4*)a2)[2] = p[2]; ((float4*)a2)[3] = p[3];
    p = (const float4*)(z4 + (size_t)n * 16);
    ((float4*)a4)[0] = p[0]; ((float4*)a4)[1] = p[1];
    ((float4*)a4)[2] = p[2]; ((float4*)a4)[3] = p[3];
    p = (const float4*)(pmy + (size_t)n * 16);
    ((float4*)py)[0] = p[0]; ((float4*)py)[1] = p[1];
    ((float4*)py)[2] = p[2]; ((float4*)py)[3] = p[3];
    dg = deg[n];
  } else {
#pragma unroll
    for (int i = 0; i < 16; i++) { fa[i] = a1[i] = a2[i] = a4[i] = py[i] = 0.f; }
  }

  float out[16];
#pragma unroll
  for (int o = 0; o < 16; o++) {
    float a = sB[o];
#pragma unroll
    for (int i = 0; i < 16; i++) {
      a += fa[i] * (sWp[i * 16 + o] + dg * sWd[i * 16 + o]);
      a += a1[i] * sWr[i * 16 + o];
      a += a2[i] * sWr[256 + i * 16 + o];
      a += a4[i] * sWr[512 + i * 16 + o];
      a += py[i] * sWf[i * 16 + o];
    }
    out[o] = (o >= 8) ? fmaxf(a, 0.f) : a;
  }

  if (valid) {
    float4* r = (float4*)(result + (size_t)n * 16);
    r[0] = ((float4*)out)[0]; r[1] = ((float4*)out)[1];
    r[2] = ((float4*)out)[2]; r[3] = ((float4*)out)[3];
  } else {
#pragma unroll
    for (int o = 0; o < 16; o++) out[o] = 0.f;
  }

#pragma unroll
  for (int o = 0; o < 16; o++) {
    float s = out[o];
    float q = out[o] * out[o];
#pragma unroll
    for (int m = 32; m >= 1; m >>= 1) {
      s += __shfl_xor(s, m, 64);
      q += __shfl_xor(q, m, 64);
    }
    if ((t & 63) == 0) {
      atomicAdd(&stats[o], s);
      atomicAdd(&stats[16 + o], q);
    }
  }
}

// ---------------------------------------------------------------------------
__global__ void bn_coeffs(float* __restrict__ stats,
                          const float* __restrict__ gamma,
                          const float* __restrict__ beta) {
  int t = threadIdx.x;
  if (t < 16) {
    float mean = stats[t] * (1.0f / Nn);
    float var  = stats[16 + t] * (1.0f / Nn) - mean * mean;
    float sc   = gamma[t] * rsqrtf(var + 1e-5f);
    stats[32 + t] = sc;
    stats[48 + t] = beta[t] - mean * sc;
  }
}

__global__ __launch_bounds__(256) void bn_apply(
    float* __restrict__ result, const float* __restrict__ stats) {
  int idx = blockIdx.x * 256 + threadIdx.x;          // over Nn*4
  if (idx >= Nn * 4) return;
  int c = (idx & 3) * 4;
  float4 r = ((const float4*)result)[idx];
  float4 o;
  o.x = r.x * stats[32 + c + 0] + stats[48 + c + 0];
  o.y = r.y * stats[32 + c + 1] + stats[48 + c + 1];
  o.z = r.z * stats[32 + c + 2] + stats[48 + c + 2];
  o.w = r.w * stats[32 + c + 3] + stats[48 + c + 3];
  ((float4*)result)[idx] = o;
}

// ---------------------------------------------------------------------------
extern "C" void kernel_launch(void* const* d_in, const int* in_sizes, int n_in,
                              void* d_out, int out_size, void* d_ws, size_t ws_size,
                              hipStream_t stream) {
  const float* feat_a  = (const float*)d_in[0];
  const float* feat_b  = (const float*)d_in[1];
  const float* deg     = (const float*)d_in[2];
  const float* pm_vals = (const float*)d_in[3];
  const float* W_prev  = (const float*)d_in[4];
  const float* b_prev  = (const float*)d_in[5];
  const float* W_deg   = (const float*)d_in[6];
  const float* b_deg   = (const float*)d_in[7];
  const float* W_rad   = (const float*)d_in[8];
  const float* b_rad   = (const float*)d_in[9];
  const float* W_fuse  = (const float*)d_in[10];
  const float* b_fuse  = (const float*)d_in[11];
  const float* bn_g    = (const float*)d_in[12];
  const float* bn_b    = (const float*)d_in[13];
  const int*   src     = (const int*)d_in[14];
  const int*   dst     = (const int*)d_in[15];
  const int*   pm_rows = (const int*)d_in[16];
  const int*   pm_cols = (const int*)d_in[17];

  int* ws = (int*)d_ws;
  int*  csr_src = ws;                                  // Ee ints
  int2* bp      = (int2*)(ws + (size_t)Ee);            // NNZn int2
  float* pm_y   = (float*)(ws + (size_t)Ee + 2 * (size_t)NNZn);  // NF floats
  int* rp_e  = (int*)(pm_y + NF);                      // Nn+1
  int* rp_p  = rp_e + (Nn + 1);                        // Nn+1
  int* cur_e = rp_p + (Nn + 1);                        // Nn (also scan temp)
  int* cur_p = cur_e + Nn;                             // Nn
  float* stats = (float*)(cur_p + Nn);                 // 64
  // cnt + bsum alias the bp region: dead before the bp scatter writes it.
  int* cnt_e = (int*)bp;                               // Nn
  int* cnt_p = cnt_e + Nn;                             // Nn
  int* bsum  = cnt_p + Nn;                             // 2*SCAN_NB
  // z buffers alias bp region (bp dead after pm_csr): 4*NF <= 2*NNZn
  float* z1 = (float*)bp;
  float* z2 = z1 + (size_t)NF;
  float* z3 = z2 + (size_t)NF;
  float* z4 = z3 + (size_t)NF;
  float* result = (float*)d_out;

  // zero histograms + block sums + stats
  hipMemsetAsync(cnt_e, 0, (size_t)(2 * Nn + 2 * SCAN_NB) * sizeof(int), stream);
  hipMemsetAsync(stats, 0, 64 * sizeof(float), stream);

  hist_kernel<<<Ee / 1024, 256, 0, stream>>>(dst, Ee, cnt_e);
  hist_kernel<<<NNZn / 1024, 256, 0, stream>>>(pm_rows, NNZn, cnt_p);

  scan_local<<<dim3(SCAN_NB, 2), 1024, 0, stream>>>(
      cnt_e, cnt_p, cur_e, cur_p, bsum);
  scan_bsum<<<2, 128, 0, stream>>>(bsum);
  scan_fix<<<dim3(SCAN_NB, 2), 1024, 0, stream>>>(
      cnt_e, cnt_p, cur_e, cur_p, rp_e, rp_p, bsum);

  bin_edges_csr<<<Ee / 1024, 256, 0, stream>>>(dst, src, cur_e, csr_src);
  bin_pm_csr<<<NNZn / 1024, 256, 0, stream>>>(pm_rows, pm_cols, pm_vals,
                                              cur_p, bp);

  // pm first: consumes bp, freeing it for z1..z4
  int rowblocks = (Nn * 16) / 256;   // 6250
  pm_csr<<<rowblocks, 256, 0, stream>>>(feat_b, bp, rp_p, pm_y);

  hop_csr<<<rowblocks, 256, 0, stream>>>(feat_a, z1, csr_src, rp_e);
  hop_csr<<<rowblocks, 256, 0, stream>>>(z1, z2, csr_src, rp_e);
  hop_csr<<<rowblocks, 256, 0, stream>>>(z2, z3, csr_src, rp_e);
  hop_csr<<<rowblocks, 256, 0, stream>>>(z3, z4, csr_src, rp_e);

  int fuse_blocks = (Nn + 255) / 256;
  fuse_kernel<<<fuse_blocks, 256, 0, stream>>>(
      feat_a, deg, z1, z2, z4, pm_y,
      W_prev, b_prev, W_deg, b_deg, W_rad, b_rad, W_fuse, b_fuse,
      result, stats);

  bn_coeffs<<<1, 64, 0, stream>>>(stats, bn_g, bn_b);

  int bn_blocks = (Nn * 4 + 255) / 256;
  bn_apply<<<bn_blocks, 256, 0, stream>>>(result, stats);
}

// Round 2
// 1446.557 us; speedup vs baseline: 1.7624x; 1.4342x over previous
//
#include <hip/hip_runtime.h>
#include <math.h>

#define Nn    100000
#define Ee    3200000
#define NNZn  6400000
#define NF    (Nn * 16)     // floats per node-feature buffer
#define K     1024          // coarse row buckets
#define RPB   98            // rows per bucket = ceil(Nn/K)
#define CHUNK 16384         // items per binning block

// ---------------------------------------------------------------------------
// Coarse count: per-block LDS histogram of key/RPB, one global atomic/bucket.
// (proven round-0 kernel)
// ---------------------------------------------------------------------------
__global__ __launch_bounds__(256) void count_kernel(
    const int* __restrict__ keys, int n, int* __restrict__ tot) {
  __shared__ int h[K];
  int t = threadIdx.x;
  for (int i = t; i < K; i += 256) h[i] = 0;
  __syncthreads();
  int base = blockIdx.x * CHUNK;
  int end = min(base + CHUNK, n);
  for (int i = base + t; i < end; i += 256) atomicAdd(&h[keys[i] / RPB], 1);
  __syncthreads();
  for (int i = t; i < K; i += 256)
    if (h[i]) atomicAdd(&tot[i], h[i]);
}

// ---------------------------------------------------------------------------
// Exclusive scan of bucket totals -> bucket_start + cursor. 2 blocks x 1024.
// (proven round-0 kernel)
// ---------------------------------------------------------------------------
__global__ __launch_bounds__(1024) void scan_kernel(
    const int* __restrict__ tot_e, const int* __restrict__ tot_p,
    int* __restrict__ bs_e, int* __restrict__ cur_e,
    int* __restrict__ bs_p, int* __restrict__ cur_p) {
  const int* tot = (blockIdx.x == 0) ? tot_e : tot_p;
  int* bs  = (blockIdx.x == 0) ? bs_e  : bs_p;
  int* cur = (blockIdx.x == 0) ? cur_e : cur_p;
  __shared__ int s[K];
  int t = threadIdx.x;
  s[t] = tot[t];
  __syncthreads();
  for (int off = 1; off < K; off <<= 1) {
    int v = (t >= off) ? s[t - off] : 0;
    __syncthreads();
    s[t] += v;
    __syncthreads();
  }
  int excl = t ? s[t - 1] : 0;
  bs[t] = excl;
  cur[t] = excl;
  if (t == K - 1) bs[K] = s[K - 1];
}

// ---------------------------------------------------------------------------
// Coarse bin edges: binned[pos] = (local_row<<17) | src.  Block-batched
// cursor reservation -> contiguous write runs. (proven round-0 kernel)
// ---------------------------------------------------------------------------
__global__ __launch_bounds__(256) void bin_edges(
    const int* __restrict__ dst, const int* __restrict__ src,
    int* __restrict__ cur, int* __restrict__ binned) {
  __shared__ int h[K];
  int t = threadIdx.x;
  for (int i = t; i < K; i += 256) h[i] = 0;
  __syncthreads();
  int base = blockIdx.x * CHUNK;
  int end = min(base + CHUNK, Ee);
  for (int i = base + t; i < end; i += 256) atomicAdd(&h[dst[i] / RPB], 1);
  __syncthreads();
  for (int k = t; k < K; k += 256) {
    int c = h[k];
    h[k] = c ? atomicAdd(&cur[k], c) : 0;
  }
  __syncthreads();
  for (int i = base + t; i < end; i += 256) {
    int d = dst[i];
    int k = d / RPB;
    int lr = d - k * RPB;
    int pos = atomicAdd(&h[k], 1);
    binned[pos] = (lr << 17) | src[i];
  }
}

// ---------------------------------------------------------------------------
// Coarse bin pm: bp[pos] = { (local_row<<23)|col , bits(val) }
// (proven round-0 kernel)
// ---------------------------------------------------------------------------
__global__ __launch_bounds__(256) void bin_pm(
    const int* __restrict__ rows, const int* __restrict__ cols,
    const float* __restrict__ vals,
    int* __restrict__ cur, int2* __restrict__ bp) {
  __shared__ int h[K];
  int t = threadIdx.x;
  for (int i = t; i < K; i += 256) h[i] = 0;
  __syncthreads();
  int base = blockIdx.x * CHUNK;
  int end = min(base + CHUNK, NNZn);
  for (int i = base + t; i < end; i += 256) atomicAdd(&h[rows[i] / RPB], 1);
  __syncthreads();
  for (int k = t; k < K; k += 256) {
    int c = h[k];
    h[k] = c ? atomicAdd(&cur[k], c) : 0;
  }
  __syncthreads();
  for (int i = base + t; i < end; i += 256) {
    int r = rows[i];
    int k = r / RPB;
    int lr = r - k * RPB;
    int pos = atomicAdd(&h[k], 1);
    bp[pos] = make_int2((lr << 23) | cols[i], __float_as_int(vals[i]));
  }
}

// ---------------------------------------------------------------------------
// Per-bucket sort (edges): LDS 98-row hist + scan, write row_ptr, scatter
// into contiguous CSR run [bs[b], bs[b+1]).  Writes land in a ~12 KB window.
// ---------------------------------------------------------------------------
__global__ __launch_bounds__(256) void sort_edges(
    const int* __restrict__ be, const int* __restrict__ bs,
    int* __restrict__ csr, int* __restrict__ rp) {
  __shared__ int hist[RPB];
  __shared__ int sc[128];
  int b = blockIdx.x, t = threadIdx.x;
  if (t < RPB) hist[t] = 0;
  __syncthreads();
  int s0 = bs[b], s1 = bs[b + 1];
  for (int i = s0 + t; i < s1; i += 256)
    atomicAdd(&hist[be[i] >> 17], 1);
  __syncthreads();
  if (t < 128) sc[t] = (t < RPB) ? hist[t] : 0;
  __syncthreads();
  for (int off = 1; off < 128; off <<= 1) {
    int v = 0;
    if (t < 128 && t >= off) v = sc[t - off];
    __syncthreads();
    if (t < 128) sc[t] += v;
    __syncthreads();
  }
  int r0 = b * RPB;
  if (t < RPB) {
    int r = r0 + t;
    if (r < Nn) rp[r + 1] = s0 + sc[t];
    hist[t] = s0 + sc[t] - hist[t];  // exclusive start = cursor
  }
  if (b == 0 && t == 0) rp[0] = 0;
  __syncthreads();
  for (int i = s0 + t; i < s1; i += 256) {
    int p = be[i];
    int pos = atomicAdd(&hist[p >> 17], 1);
    csr[pos] = p & 0x1FFFF;
  }
}

// ---------------------------------------------------------------------------
// Per-bucket sort (pm), phased: buckets [b0, b0+grid) scatter into the
// 12.8MB staging region with PHASE-LOCAL offsets; rp_p entries for this
// phase's rows are phase-local indices into that region.
// ---------------------------------------------------------------------------
__global__ __launch_bounds__(256) void sort_pm(
    const int2* __restrict__ bpi, const int* __restrict__ bs, int b0,
    int2* __restrict__ dcsr, int* __restrict__ rp) {
  __shared__ int hist[RPB];
  __shared__ int sc[128];
  int b = b0 + blockIdx.x, t = threadIdx.x;
  if (t < RPB) hist[t] = 0;
  __syncthreads();
  int s0 = bs[b], s1 = bs[b + 1];
  int base = s0 - bs[b0];          // phase-local base
  for (int i = s0 + t; i < s1; i += 256)
    atomicAdd(&hist[bpi[i].x >> 23], 1);
  __syncthreads();
  if (t < 128) sc[t] = (t < RPB) ? hist[t] : 0;
  __syncthreads();
  for (int off = 1; off < 128; off <<= 1) {
    int v = 0;
    if (t < 128 && t >= off) v = sc[t - off];
    __syncthreads();
    if (t < 128) sc[t] += v;
    __syncthreads();
  }
  int r0 = b * RPB;
  if (t < RPB) {
    int r = r0 + t;
    if (r < Nn) rp[r + 1] = base + sc[t];
    hist[t] = base + sc[t] - hist[t];  // phase-local exclusive cursor
  }
  if (b == b0 && t == 0) rp[r0] = 0;
  __syncthreads();
  for (int i = s0 + t; i < s1; i += 256) {
    int2 e = bpi[i];
    int pos = atomicAdd(&hist[e.x >> 23], 1);
    dcsr[pos] = make_int2(e.x & 0x7FFFFF, e.y);
  }
}

// ---------------------------------------------------------------------------
// CSR hop, float4: 4 lanes per row, 8 float4 gathers in flight per lane.
// ---------------------------------------------------------------------------
__global__ __launch_bounds__(256) void hop_csr4(
    const float* __restrict__ zin, float* __restrict__ zout,
    const int* __restrict__ cs, const int* __restrict__ rp) {
  int gid = (blockIdx.x * 256 + threadIdx.x) >> 2;
  int q = (threadIdx.x & 3) * 4;
  if (gid >= Nn) return;
  int j = rp[gid], e = rp[gid + 1];
  float ax = 0.f, ay = 0.f, az = 0.f, aw = 0.f;
  for (; j + 8 <= e; j += 8) {
    int s0 = cs[j],     s1 = cs[j + 1], s2 = cs[j + 2], s3 = cs[j + 3];
    int s4 = cs[j + 4], s5 = cs[j + 5], s6 = cs[j + 6], s7 = cs[j + 7];
    float4 x0 = *(const float4*)(zin + (size_t)s0 * 16 + q);
    float4 x1 = *(const float4*)(zin + (size_t)s1 * 16 + q);
    float4 x2 = *(const float4*)(zin + (size_t)s2 * 16 + q);
    float4 x3 = *(const float4*)(zin + (size_t)s3 * 16 + q);
    float4 x4 = *(const float4*)(zin + (size_t)s4 * 16 + q);
    float4 x5 = *(const float4*)(zin + (size_t)s5 * 16 + q);
    float4 x6 = *(const float4*)(zin + (size_t)s6 * 16 + q);
    float4 x7 = *(const float4*)(zin + (size_t)s7 * 16 + q);
    ax += ((x0.x + x1.x) + (x2.x + x3.x)) + ((x4.x + x5.x) + (x6.x + x7.x));
    ay += ((x0.y + x1.y) + (x2.y + x3.y)) + ((x4.y + x5.y) + (x6.y + x7.y));
    az += ((x0.z + x1.z) + (x2.z + x3.z)) + ((x4.z + x5.z) + (x6.z + x7.z));
    aw += ((x0.w + x1.w) + (x2.w + x3.w)) + ((x4.w + x5.w) + (x6.w + x7.w));
  }
  for (; j < e; ++j) {
    float4 x = *(const float4*)(zin + (size_t)cs[j] * 16 + q);
    ax += x.x; ay += x.y; az += x.z; aw += x.w;
  }
  *(float4*)(zout + (size_t)gid * 16 + q) = make_float4(ax, ay, az, aw);
}

// ---------------------------------------------------------------------------
// CSR pm, float4, phased over row range [r0, r1); rp holds phase-local
// offsets into the staging region.
// ---------------------------------------------------------------------------
__global__ __launch_bounds__(256) void pm_csr4(
    const float* __restrict__ fb, const int2* __restrict__ bp,
    const int* __restrict__ rp, float* __restrict__ pmy,
    int r0, int r1) {
  int gid = r0 + ((blockIdx.x * 256 + threadIdx.x) >> 2);
  int q = (threadIdx.x & 3) * 4;
  if (gid >= r1) return;
  int j = rp[gid], e = rp[gid + 1];
  float ax = 0.f, ay = 0.f, az = 0.f, aw = 0.f;
  for (; j + 8 <= e; j += 8) {
    int2 e0 = bp[j];     int2 e1 = bp[j + 1];
    int2 e2 = bp[j + 2]; int2 e3 = bp[j + 3];
    int2 e4 = bp[j + 4]; int2 e5 = bp[j + 5];
    int2 e6 = bp[j + 6]; int2 e7 = bp[j + 7];
    float4 x0 = *(const float4*)(fb + (size_t)e0.x * 16 + q);
    float4 x1 = *(const float4*)(fb + (size_t)e1.x * 16 + q);
    float4 x2 = *(const float4*)(fb + (size_t)e2.x * 16 + q);
    float4 x3 = *(const float4*)(fb + (size_t)e3.x * 16 + q);
    float4 x4 = *(const float4*)(fb + (size_t)e4.x * 16 + q);
    float4 x5 = *(const float4*)(fb + (size_t)e5.x * 16 + q);
    float4 x6 = *(const float4*)(fb + (size_t)e6.x * 16 + q);
    float4 x7 = *(const float4*)(fb + (size_t)e7.x * 16 + q);
    float v0 = __int_as_float(e0.y), v1 = __int_as_float(e1.y);
    float v2 = __int_as_float(e2.y), v3 = __int_as_float(e3.y);
    float v4 = __int_as_float(e4.y), v5 = __int_as_float(e5.y);
    float v6 = __int_as_float(e6.y), v7 = __int_as_float(e7.y);
    ax = fmaf(v0, x0.x, ax); ay = fmaf(v0, x0.y, ay);
    az = fmaf(v0, x0.z, az); aw = fmaf(v0, x0.w, aw);
    ax = fmaf(v1, x1.x, ax); ay = fmaf(v1, x1.y, ay);
    az = fmaf(v1, x1.z, az); aw = fmaf(v1, x1.w, aw);
    ax = fmaf(v2, x2.x, ax); ay = fmaf(v2, x2.y, ay);
    az = fmaf(v2, x2.z, az); aw = fmaf(v2, x2.w, aw);
    ax = fmaf(v3, x3.x, ax); ay = fmaf(v3, x3.y, ay);
    az = fmaf(v3, x3.z, az); aw = fmaf(v3, x3.w, aw);
    ax = fmaf(v4, x4.x, ax); ay = fmaf(v4, x4.y, ay);
    az = fmaf(v4, x4.z, az); aw = fmaf(v4, x4.w, aw);
    ax = fmaf(v5, x5.x, ax); ay = fmaf(v5, x5.y, ay);
    az = fmaf(v5, x5.z, az); aw = fmaf(v5, x5.w, aw);
    ax = fmaf(v6, x6.x, ax); ay = fmaf(v6, x6.y, ay);
    az = fmaf(v6, x6.z, az); aw = fmaf(v6, x6.w, aw);
    ax = fmaf(v7, x7.x, ax); ay = fmaf(v7, x7.y, ay);
    az = fmaf(v7, x7.z, az); aw = fmaf(v7, x7.w, aw);
  }
  for (; j < e; ++j) {
    int2 ee = bp[j];
    float4 x = *(const float4*)(fb + (size_t)ee.x * 16 + q);
    float v = __int_as_float(ee.y);
    ax = fmaf(v, x.x, ax); ay = fmaf(v, x.y, ay);
    az = fmaf(v, x.z, az); aw = fmaf(v, x.w, aw);
  }
  *(float4*)(pmy + (size_t)gid * 16 + q) = make_float4(ax, ay, az, aw);
}

// ---------------------------------------------------------------------------
// Fused per-node projections + ReLU(second half) + BN-stat partial reduction.
// (unchanged, verified)
// ---------------------------------------------------------------------------
__global__ __launch_bounds__(256) void fuse_kernel(
    const float* __restrict__ feat_a, const float* __restrict__ deg,
    const float* __restrict__ z1, const float* __restrict__ z2,
    const float* __restrict__ z4, const float* __restrict__ pmy,
    const float* __restrict__ Wprev, const float* __restrict__ bprev,
    const float* __restrict__ Wdeg,  const float* __restrict__ bdeg,
    const float* __restrict__ Wrad,  const float* __restrict__ brad,
    const float* __restrict__ Wfuse, const float* __restrict__ bfuse,
    float* __restrict__ result, float* __restrict__ stats) {
  __shared__ float sWp[256], sWd[256], sWr[768], sWf[256], sB[16];
  int t = threadIdx.x;
  sWp[t] = Wprev[t];
  sWd[t] = Wdeg[t];
  sWf[t] = Wfuse[t];
  for (int i = t; i < 768; i += 256) sWr[i] = Wrad[i];
  if (t < 16)
    sB[t] = bprev[t] + bdeg[t] + brad[t] + brad[16 + t] + brad[32 + t] + bfuse[t];
  __syncthreads();

  int n = blockIdx.x * 256 + t;
  bool valid = n < Nn;

  float fa[16], a1[16], a2[16], a4[16], py[16];
  float dg = 0.f;
  if (valid) {
    const float4* p;
    p = (const float4*)(feat_a + (size_t)n * 16);
    ((float4*)fa)[0] = p[0]; ((float4*)fa)[1] = p[1];
    ((float4*)fa)[2] = p[2]; ((float4*)fa)[3] = p[3];
    p = (const float4*)(z1 + (size_t)n * 16);
    ((float4*)a1)[0] = p[0]; ((float4*)a1)[1] = p[1];
    ((float4*)a1)[2] = p[2]; ((float4*)a1)[3] = p[3];
    p = (const float4*)(z2 + (size_t)n * 16);
    ((float4*)a2)[0] = p[0]; ((float4*)a2)[1] = p[1];
    ((float4*)a2)[2] = p[2]; ((float4*)a2)[3] = p[3];
    p = (const float4*)(z4 + (size_t)n * 16);
    ((float4*)a4)[0] = p[0]; ((float4*)a4)[1] = p[1];
    ((float4*)a4)[2] = p[2]; ((float4*)a4)[3] = p[3];
    p = (const float4*)(pmy + (size_t)n * 16);
    ((float4*)py)[0] = p[0]; ((float4*)py)[1] = p[1];
    ((float4*)py)[2] = p[2]; ((float4*)py)[3] = p[3];
    dg = deg[n];
  } else {
#pragma unroll
    for (int i = 0; i < 16; i++) { fa[i] = a1[i] = a2[i] = a4[i] = py[i] = 0.f; }
  }

  float out[16];
#pragma unroll
  for (int o = 0; o < 16; o++) {
    float a = sB[o];
#pragma unroll
    for (int i = 0; i < 16; i++) {
      a += fa[i] * (sWp[i * 16 + o] + dg * sWd[i * 16 + o]);
      a += a1[i] * sWr[i * 16 + o];
      a += a2[i] * sWr[256 + i * 16 + o];
      a += a4[i] * sWr[512 + i * 16 + o];
      a += py[i] * sWf[i * 16 + o];
    }
    out[o] = (o >= 8) ? fmaxf(a, 0.f) : a;
  }

  if (valid) {
    float4* r = (float4*)(result + (size_t)n * 16);
    r[0] = ((float4*)out)[0]; r[1] = ((float4*)out)[1];
    r[2] = ((float4*)out)[2]; r[3] = ((float4*)out)[3];
  } else {
#pragma unroll
    for (int o = 0; o < 16; o++) out[o] = 0.f;
  }

#pragma unroll
  for (int o = 0; o < 16; o++) {
    float s = out[o];
    float qq = out[o] * out[o];
#pragma unroll
    for (int m = 32; m >= 1; m >>= 1) {
      s += __shfl_xor(s, m, 64);
      qq += __shfl_xor(qq, m, 64);
    }
    if ((t & 63) == 0) {
      atomicAdd(&stats[o], s);
      atomicAdd(&stats[16 + o], qq);
    }
  }
}

// ---------------------------------------------------------------------------
__global__ void bn_coeffs(float* __restrict__ stats,
                          const float* __restrict__ gamma,
                          const float* __restrict__ beta) {
  int t = threadIdx.x;
  if (t < 16) {
    float mean = stats[t] * (1.0f / Nn);
    float var  = stats[16 + t] * (1.0f / Nn) - mean * mean;
    float sc   = gamma[t] * rsqrtf(var + 1e-5f);
    stats[32 + t] = sc;
    stats[48 + t] = beta[t] - mean * sc;
  }
}

__global__ __launch_bounds__(256) void bn_apply(
    float* __restrict__ result, const float* __restrict__ stats) {
  int idx = blockIdx.x * 256 + threadIdx.x;          // over Nn*4
  if (idx >= Nn * 4) return;
  int c = (idx & 3) * 4;
  float4 r = ((const float4*)result)[idx];
  float4 o;
  o.x = r.x * stats[32 + c + 0] + stats[48 + c + 0];
  o.y = r.y * stats[32 + c + 1] + stats[48 + c + 1];
  o.z = r.z * stats[32 + c + 2] + stats[48 + c + 2];
  o.w = r.w * stats[32 + c + 3] + stats[48 + c + 3];
  ((float4*)result)[idx] = o;
}

// ---------------------------------------------------------------------------
extern "C" void kernel_launch(void* const* d_in, const int* in_sizes, int n_in,
                              void* d_out, int out_size, void* d_ws, size_t ws_size,
                              hipStream_t stream) {
  const float* feat_a  = (const float*)d_in[0];
  const float* feat_b  = (const float*)d_in[1];
  const float* deg     = (const float*)d_in[2];
  const float* pm_vals = (const float*)d_in[3];
  const float* W_prev  = (const float*)d_in[4];
  const float* b_prev  = (const float*)d_in[5];
  const float* W_deg   = (const float*)d_in[6];
  const float* b_deg   = (const float*)d_in[7];
  const float* W_rad   = (const float*)d_in[8];
  const float* b_rad   = (const float*)d_in[9];
  const float* W_fuse  = (const float*)d_in[10];
  const float* b_fuse  = (const float*)d_in[11];
  const float* bn_g    = (const float*)d_in[12];
  const float* bn_b    = (const float*)d_in[13];
  const int*   src     = (const int*)d_in[14];
  const int*   dst     = (const int*)d_in[15];
  const int*   pm_rows = (const int*)d_in[16];
  const int*   pm_cols = (const int*)d_in[17];

  int* ws = (int*)d_ws;
  // Region A (Ee ints = 12.8MB): pm sort staging (per-phase), then csr_src.
  // Region B (2*NNZ ints = 51.2MB): bucket-binned pm, then bucket-binned
  //   edges [0..Ee), then z1..z4 (4*NF floats = 25.6MB).
  int*   A    = ws;
  int*   B    = ws + (size_t)Ee;
  float* pm_y = (float*)(ws + (size_t)Ee + 2 * (size_t)NNZn);   // NF floats
  int*   T    = (int*)(pm_y + NF);
  int*   tot_e = T;                       // K
  int*   tot_p = T + K;                   // K
  float* stats = (float*)(T + 2 * K);     // 64
  int*   bs_e  = T + 2 * K + 64;          // K+1
  int*   cur_e = bs_e + K + 1;            // K
  int*   bs_p  = cur_e + K;               // K+1
  int*   cur_p = bs_p + K + 1;            // K
  int*   rp_e  = cur_p + K;               // Nn+1
  int*   rp_p  = rp_e + Nn + 1;           // Nn+1

  int2*  bp       = (int2*)B;
  int2*  dcsr     = (int2*)A;
  int*   binned_e = B;
  int*   csr_src  = A;
  float* z1 = (float*)B;
  float* z2 = z1 + (size_t)NF;
  float* z3 = z2 + (size_t)NF;
  float* z4 = z3 + (size_t)NF;
  float* result = (float*)d_out;

  // zero coarse totals + stats (contiguous)
  hipMemsetAsync(T, 0, (size_t)(2 * K + 64) * sizeof(int), stream);

  int cb_e = (Ee + CHUNK - 1) / CHUNK;     // 196
  int cb_p = (NNZn + CHUNK - 1) / CHUNK;   // 391
  count_kernel<<<cb_e, 256, 0, stream>>>(dst, Ee, tot_e);
  count_kernel<<<cb_p, 256, 0, stream>>>(pm_rows, NNZn, tot_p);
  scan_kernel<<<2, 1024, 0, stream>>>(tot_e, tot_p, bs_e, cur_e, bs_p, cur_p);

  // pm: coarse bin -> phased {bucket sort into A, consume into pm_y}
  bin_pm<<<cb_p, 256, 0, stream>>>(pm_rows, pm_cols, pm_vals, cur_p, bp);
  const int pb[6] = {0, 205, 410, 615, 820, 1024};
  for (int q = 0; q < 5; ++q) {
    int b0 = pb[q], b1 = pb[q + 1];
    sort_pm<<<b1 - b0, 256, 0, stream>>>(bp, bs_p, b0, dcsr, rp_p);
    int r0 = b0 * RPB;
    int r1 = (b1 * RPB < Nn) ? b1 * RPB : Nn;
    int nb = ((r1 - r0) * 4 + 255) / 256;
    pm_csr4<<<nb, 256, 0, stream>>>(feat_b, dcsr, rp_p, pm_y, r0, r1);
  }

  // edges: coarse bin into B[0..Ee) (bp dead), sort into A (staging dead)
  bin_edges<<<cb_e, 256, 0, stream>>>(dst, src, cur_e, binned_e);
  sort_edges<<<K, 256, 0, stream>>>(binned_e, bs_e, csr_src, rp_e);

  // hops (z buffers overwrite binned_e region, dead after sort_edges)
  int hop_blocks = (Nn * 4 + 255) / 256;   // 1563
  hop_csr4<<<hop_blocks, 256, 0, stream>>>(feat_a, z1, csr_src, rp_e);
  hop_csr4<<<hop_blocks, 256, 0, stream>>>(z1, z2, csr_src, rp_e);
  hop_csr4<<<hop_blocks, 256, 0, stream>>>(z2, z3, csr_src, rp_e);
  hop_csr4<<<hop_blocks, 256, 0, stream>>>(z3, z4, csr_src, rp_e);

  int fuse_blocks = (Nn + 255) / 256;
  fuse_kernel<<<fuse_blocks, 256, 0, stream>>>(
      feat_a, deg, z1, z2, z4, pm_y,
      W_prev, b_prev, W_deg, b_deg, W_rad, b_rad, W_fuse, b_fuse,
      result, stats);

  bn_coeffs<<<1, 64, 0, stream>>>(stats, bn_g, bn_b);

  int bn_blocks = (Nn * 4 + 255) / 256;
  bn_apply<<<bn_blocks, 256, 0, stream>>>(result, stats);
}

// Round 3
// 1147.843 us; speedup vs baseline: 2.2211x; 1.2602x over previous
//
#include <hip/hip_runtime.h>
#include <math.h>

#define Nn    100000
#define Ee    3200000
#define NNZn  6400000
#define NF    (Nn * 16)     // floats per node-feature buffer
#define K     1024          // coarse row buckets
#define RPB   98            // rows per bucket = ceil(Nn/K)
#define CHUNK 16384         // items per binning block

// ---------------------------------------------------------------------------
// Coarse count: per-block LDS histogram of key/RPB, one global atomic/bucket.
// ---------------------------------------------------------------------------
__global__ __launch_bounds__(256) void count_kernel(
    const int* __restrict__ keys, int n, int* __restrict__ tot) {
  __shared__ int h[K];
  int t = threadIdx.x;
  for (int i = t; i < K; i += 256) h[i] = 0;
  __syncthreads();
  int base = blockIdx.x * CHUNK;
  int end = min(base + CHUNK, n);
  for (int i = base + t; i < end; i += 256) atomicAdd(&h[keys[i] / RPB], 1);
  __syncthreads();
  for (int i = t; i < K; i += 256)
    if (h[i]) atomicAdd(&tot[i], h[i]);
}

// ---------------------------------------------------------------------------
// Exclusive scan of bucket totals -> bucket_start + cursor. 2 blocks x 1024.
// ---------------------------------------------------------------------------
__global__ __launch_bounds__(1024) void scan_kernel(
    const int* __restrict__ tot_e, const int* __restrict__ tot_p,
    int* __restrict__ bs_e, int* __restrict__ cur_e,
    int* __restrict__ bs_p, int* __restrict__ cur_p) {
  const int* tot = (blockIdx.x == 0) ? tot_e : tot_p;
  int* bs  = (blockIdx.x == 0) ? bs_e  : bs_p;
  int* cur = (blockIdx.x == 0) ? cur_e : cur_p;
  __shared__ int s[K];
  int t = threadIdx.x;
  s[t] = tot[t];
  __syncthreads();
  for (int off = 1; off < K; off <<= 1) {
    int v = (t >= off) ? s[t - off] : 0;
    __syncthreads();
    s[t] += v;
    __syncthreads();
  }
  int excl = t ? s[t - 1] : 0;
  bs[t] = excl;
  cur[t] = excl;
  if (t == K - 1) bs[K] = s[K - 1];
}

// ---------------------------------------------------------------------------
// Coarse bin edges: binned[pos] = (local_row<<17) | src.
// ---------------------------------------------------------------------------
__global__ __launch_bounds__(256) void bin_edges(
    const int* __restrict__ dst, const int* __restrict__ src,
    int* __restrict__ cur, int* __restrict__ binned) {
  __shared__ int h[K];
  int t = threadIdx.x;
  for (int i = t; i < K; i += 256) h[i] = 0;
  __syncthreads();
  int base = blockIdx.x * CHUNK;
  int end = min(base + CHUNK, Ee);
  for (int i = base + t; i < end; i += 256) atomicAdd(&h[dst[i] / RPB], 1);
  __syncthreads();
  for (int k = t; k < K; k += 256) {
    int c = h[k];
    h[k] = c ? atomicAdd(&cur[k], c) : 0;
  }
  __syncthreads();
  for (int i = base + t; i < end; i += 256) {
    int d = dst[i];
    int k = d / RPB;
    int lr = d - k * RPB;
    int pos = atomicAdd(&h[k], 1);
    binned[pos] = (lr << 17) | src[i];
  }
}

// ---------------------------------------------------------------------------
// Coarse bin pm: bp[pos] = { (local_row<<23)|col , bits(val) }
// ---------------------------------------------------------------------------
__global__ __launch_bounds__(256) void bin_pm(
    const int* __restrict__ rows, const int* __restrict__ cols,
    const float* __restrict__ vals,
    int* __restrict__ cur, int2* __restrict__ bp) {
  __shared__ int h[K];
  int t = threadIdx.x;
  for (int i = t; i < K; i += 256) h[i] = 0;
  __syncthreads();
  int base = blockIdx.x * CHUNK;
  int end = min(base + CHUNK, NNZn);
  for (int i = base + t; i < end; i += 256) atomicAdd(&h[rows[i] / RPB], 1);
  __syncthreads();
  for (int k = t; k < K; k += 256) {
    int c = h[k];
    h[k] = c ? atomicAdd(&cur[k], c) : 0;
  }
  __syncthreads();
  for (int i = base + t; i < end; i += 256) {
    int r = rows[i];
    int k = r / RPB;
    int lr = r - k * RPB;
    int pos = atomicAdd(&h[k], 1);
    bp[pos] = make_int2((lr << 23) | cols[i], __float_as_int(vals[i]));
  }
}

// ---------------------------------------------------------------------------
// Per-bucket sort (edges): LDS 98-row hist + scan, write row_ptr, scatter
// into contiguous CSR run [bs[b], bs[b+1]).
// ---------------------------------------------------------------------------
__global__ __launch_bounds__(256) void sort_edges(
    const int* __restrict__ be, const int* __restrict__ bs,
    int* __restrict__ csr, int* __restrict__ rp) {
  __shared__ int hist[RPB];
  __shared__ int sc[128];
  int b = blockIdx.x, t = threadIdx.x;
  if (t < RPB) hist[t] = 0;
  __syncthreads();
  int s0 = bs[b], s1 = bs[b + 1];
  for (int i = s0 + t; i < s1; i += 256)
    atomicAdd(&hist[be[i] >> 17], 1);
  __syncthreads();
  if (t < 128) sc[t] = (t < RPB) ? hist[t] : 0;
  __syncthreads();
  for (int off = 1; off < 128; off <<= 1) {
    int v = 0;
    if (t < 128 && t >= off) v = sc[t - off];
    __syncthreads();
    if (t < 128) sc[t] += v;
    __syncthreads();
  }
  int r0 = b * RPB;
  if (t < RPB) {
    int r = r0 + t;
    if (r < Nn) rp[r + 1] = s0 + sc[t];
    hist[t] = s0 + sc[t] - hist[t];  // exclusive start = cursor
  }
  if (b == 0 && t == 0) rp[0] = 0;
  __syncthreads();
  for (int i = s0 + t; i < s1; i += 256) {
    int p = be[i];
    int pos = atomicAdd(&hist[p >> 17], 1);
    csr[pos] = p & 0x1FFFF;
  }
}

// ---------------------------------------------------------------------------
// Per-bucket sort (pm), phased: buckets [b0, b0+grid) scatter into the
// staging region with PHASE-LOCAL offsets.
// ---------------------------------------------------------------------------
__global__ __launch_bounds__(256) void sort_pm(
    const int2* __restrict__ bpi, const int* __restrict__ bs, int b0,
    int2* __restrict__ dcsr, int* __restrict__ rp) {
  __shared__ int hist[RPB];
  __shared__ int sc[128];
  int b = b0 + blockIdx.x, t = threadIdx.x;
  if (t < RPB) hist[t] = 0;
  __syncthreads();
  int s0 = bs[b], s1 = bs[b + 1];
  int base = s0 - bs[b0];          // phase-local base
  for (int i = s0 + t; i < s1; i += 256)
    atomicAdd(&hist[bpi[i].x >> 23], 1);
  __syncthreads();
  if (t < 128) sc[t] = (t < RPB) ? hist[t] : 0;
  __syncthreads();
  for (int off = 1; off < 128; off <<= 1) {
    int v = 0;
    if (t < 128 && t >= off) v = sc[t - off];
    __syncthreads();
    if (t < 128) sc[t] += v;
    __syncthreads();
  }
  int r0 = b * RPB;
  if (t < RPB) {
    int r = r0 + t;
    if (r < Nn) rp[r + 1] = base + sc[t];
    hist[t] = base + sc[t] - hist[t];  // phase-local exclusive cursor
  }
  if (b == b0 && t == 0) rp[r0] = 0;
  __syncthreads();
  for (int i = s0 + t; i < s1; i += 256) {
    int2 e = bpi[i];
    int pos = atomicAdd(&hist[e.x >> 23], 1);
    dcsr[pos] = make_int2(e.x & 0x7FFFFF, e.y);
  }
}

// ---------------------------------------------------------------------------
// CSR hop, float4: 4 lanes per row, 8 float4 gathers in flight per lane.
// ---------------------------------------------------------------------------
__global__ __launch_bounds__(256) void hop_csr4(
    const float* __restrict__ zin, float* __restrict__ zout,
    const int* __restrict__ cs, const int* __restrict__ rp) {
  int gid = (blockIdx.x * 256 + threadIdx.x) >> 2;
  int q = (threadIdx.x & 3) * 4;
  if (gid >= Nn) return;
  int j = rp[gid], e = rp[gid + 1];
  float ax = 0.f, ay = 0.f, az = 0.f, aw = 0.f;
  for (; j + 8 <= e; j += 8) {
    int s0 = cs[j],     s1 = cs[j + 1], s2 = cs[j + 2], s3 = cs[j + 3];
    int s4 = cs[j + 4], s5 = cs[j + 5], s6 = cs[j + 6], s7 = cs[j + 7];
    float4 x0 = *(const float4*)(zin + (size_t)s0 * 16 + q);
    float4 x1 = *(const float4*)(zin + (size_t)s1 * 16 + q);
    float4 x2 = *(const float4*)(zin + (size_t)s2 * 16 + q);
    float4 x3 = *(const float4*)(zin + (size_t)s3 * 16 + q);
    float4 x4 = *(const float4*)(zin + (size_t)s4 * 16 + q);
    float4 x5 = *(const float4*)(zin + (size_t)s5 * 16 + q);
    float4 x6 = *(const float4*)(zin + (size_t)s6 * 16 + q);
    float4 x7 = *(const float4*)(zin + (size_t)s7 * 16 + q);
    ax += ((x0.x + x1.x) + (x2.x + x3.x)) + ((x4.x + x5.x) + (x6.x + x7.x));
    ay += ((x0.y + x1.y) + (x2.y + x3.y)) + ((x4.y + x5.y) + (x6.y + x7.y));
    az += ((x0.z + x1.z) + (x2.z + x3.z)) + ((x4.z + x5.z) + (x6.z + x7.z));
    aw += ((x0.w + x1.w) + (x2.w + x3.w)) + ((x4.w + x5.w) + (x6.w + x7.w));
  }
  for (; j < e; ++j) {
    float4 x = *(const float4*)(zin + (size_t)cs[j] * 16 + q);
    ax += x.x; ay += x.y; az += x.z; aw += x.w;
  }
  *(float4*)(zout + (size_t)gid * 16 + q) = make_float4(ax, ay, az, aw);
}

// ---------------------------------------------------------------------------
// CSR pm, float4, phased over row range [r0, r1).
// ---------------------------------------------------------------------------
__global__ __launch_bounds__(256) void pm_csr4(
    const float* __restrict__ fb, const int2* __restrict__ bp,
    const int* __restrict__ rp, float* __restrict__ pmy,
    int r0, int r1) {
  int gid = r0 + ((blockIdx.x * 256 + threadIdx.x) >> 2);
  int q = (threadIdx.x & 3) * 4;
  if (gid >= r1) return;
  int j = rp[gid], e = rp[gid + 1];
  float ax = 0.f, ay = 0.f, az = 0.f, aw = 0.f;
  for (; j + 8 <= e; j += 8) {
    int2 e0 = bp[j];     int2 e1 = bp[j + 1];
    int2 e2 = bp[j + 2]; int2 e3 = bp[j + 3];
    int2 e4 = bp[j + 4]; int2 e5 = bp[j + 5];
    int2 e6 = bp[j + 6]; int2 e7 = bp[j + 7];
    float4 x0 = *(const float4*)(fb + (size_t)e0.x * 16 + q);
    float4 x1 = *(const float4*)(fb + (size_t)e1.x * 16 + q);
    float4 x2 = *(const float4*)(fb + (size_t)e2.x * 16 + q);
    float4 x3 = *(const float4*)(fb + (size_t)e3.x * 16 + q);
    float4 x4 = *(const float4*)(fb + (size_t)e4.x * 16 + q);
    float4 x5 = *(const float4*)(fb + (size_t)e5.x * 16 + q);
    float4 x6 = *(const float4*)(fb + (size_t)e6.x * 16 + q);
    float4 x7 = *(const float4*)(fb + (size_t)e7.x * 16 + q);
    float v0 = __int_as_float(e0.y), v1 = __int_as_float(e1.y);
    float v2 = __int_as_float(e2.y), v3 = __int_as_float(e3.y);
    float v4 = __int_as_float(e4.y), v5 = __int_as_float(e5.y);
    float v6 = __int_as_float(e6.y), v7 = __int_as_float(e7.y);
    ax = fmaf(v0, x0.x, ax); ay = fmaf(v0, x0.y, ay);
    az = fmaf(v0, x0.z, az); aw = fmaf(v0, x0.w, aw);
    ax = fmaf(v1, x1.x, ax); ay = fmaf(v1, x1.y, ay);
    az = fmaf(v1, x1.z, az); aw = fmaf(v1, x1.w, aw);
    ax = fmaf(v2, x2.x, ax); ay = fmaf(v2, x2.y, ay);
    az = fmaf(v2, x2.z, az); aw = fmaf(v2, x2.w, aw);
    ax = fmaf(v3, x3.x, ax); ay = fmaf(v3, x3.y, ay);
    az = fmaf(v3, x3.z, az); aw = fmaf(v3, x3.w, aw);
    ax = fmaf(v4, x4.x, ax); ay = fmaf(v4, x4.y, ay);
    az = fmaf(v4, x4.z, az); aw = fmaf(v4, x4.w, aw);
    ax = fmaf(v5, x5.x, ax); ay = fmaf(v5, x5.y, ay);
    az = fmaf(v5, x5.z, az); aw = fmaf(v5, x5.w, aw);
    ax = fmaf(v6, x6.x, ax); ay = fmaf(v6, x6.y, ay);
    az = fmaf(v6, x6.z, az); aw = fmaf(v6, x6.w, aw);
    ax = fmaf(v7, x7.x, ax); ay = fmaf(v7, x7.y, ay);
    az = fmaf(v7, x7.z, az); aw = fmaf(v7, x7.w, aw);
  }
  for (; j < e; ++j) {
    int2 ee = bp[j];
    float4 x = *(const float4*)(fb + (size_t)ee.x * 16 + q);
    float v = __int_as_float(ee.y);
    ax = fmaf(v, x.x, ax); ay = fmaf(v, x.y, ay);
    az = fmaf(v, x.z, az); aw = fmaf(v, x.w, aw);
  }
  *(float4*)(pmy + (size_t)gid * 16 + q) = make_float4(ax, ay, az, aw);
}

// ---------------------------------------------------------------------------
// Fused per-node projections + ReLU(second half) + BN-stat reduction.
// REWRITTEN: no staging arrays (previous version's float4->float[] punning
// defeated SROA -> scratch -> 336us). Stream named float4 loads, FMA
// components directly into out[16] (compile-time indexed -> registers).
// ---------------------------------------------------------------------------
__global__ __launch_bounds__(256) void fuse_kernel(
    const float* __restrict__ feat_a, const float* __restrict__ deg,
    const float* __restrict__ z1, const float* __restrict__ z2,
    const float* __restrict__ z4, const float* __restrict__ pmy,
    const float* __restrict__ Wprev, const float* __restrict__ bprev,
    const float* __restrict__ Wdeg,  const float* __restrict__ bdeg,
    const float* __restrict__ Wrad,  const float* __restrict__ brad,
    const float* __restrict__ Wfuse, const float* __restrict__ bfuse,
    float* __restrict__ result, float* __restrict__ stats) {
  __shared__ float sWp[256], sWd[256], sWr[768], sWf[256], sB[16];
  __shared__ float sstat[32];
  int t = threadIdx.x;
  sWp[t] = Wprev[t];
  sWd[t] = Wdeg[t];
  sWf[t] = Wfuse[t];
  for (int i = t; i < 768; i += 256) sWr[i] = Wrad[i];
  if (t < 32) sstat[t] = 0.f;
  if (t < 16)
    sB[t] = bprev[t] + bdeg[t] + brad[t] + brad[16 + t] + brad[32 + t] + bfuse[t];
  __syncthreads();

  int n = blockIdx.x * 256 + t;
  bool valid = n < Nn;
  int nc = valid ? n : (Nn - 1);   // clamp: loads always in-bounds

  float dg = deg[nc];
  float out[16];
#pragma unroll
  for (int o = 0; o < 16; ++o) out[o] = sB[o];

  const float4* pa = (const float4*)(feat_a + (size_t)nc * 16);
  const float4* p1 = (const float4*)(z1 + (size_t)nc * 16);
  const float4* p2 = (const float4*)(z2 + (size_t)nc * 16);
  const float4* p4 = (const float4*)(z4 + (size_t)nc * 16);
  const float4* pp = (const float4*)(pmy + (size_t)nc * 16);

#define FUSE_STEP(E, XA, X1, X2, X4, XP)                                  \
  {                                                                       \
    int i = c * 4 + (E);                                                  \
    float va = (XA);                                                      \
    float vd = dg * va;                                                   \
    float v1 = (X1), v2 = (X2), v4 = (X4), vp = (XP);                     \
    _Pragma("unroll")                                                     \
    for (int o = 0; o < 16; ++o) {                                        \
      float acc = out[o];                                                 \
      acc = fmaf(va, sWp[i * 16 + o], acc);                               \
      acc = fmaf(vd, sWd[i * 16 + o], acc);                               \
      acc = fmaf(v1, sWr[i * 16 + o], acc);                               \
      acc = fmaf(v2, sWr[256 + i * 16 + o], acc);                         \
      acc = fmaf(v4, sWr[512 + i * 16 + o], acc);                         \
      acc = fmaf(vp, sWf[i * 16 + o], acc);                               \
      out[o] = acc;                                                       \
    }                                                                     \
  }

#pragma unroll
  for (int c = 0; c < 4; ++c) {
    float4 xa = pa[c];
    float4 x1 = p1[c];
    float4 x2 = p2[c];
    float4 x4 = p4[c];
    float4 xp = pp[c];
    FUSE_STEP(0, xa.x, x1.x, x2.x, x4.x, xp.x)
    FUSE_STEP(1, xa.y, x1.y, x2.y, x4.y, xp.y)
    FUSE_STEP(2, xa.z, x1.z, x2.z, x4.z, xp.z)
    FUSE_STEP(3, xa.w, x1.w, x2.w, x4.w, xp.w)
  }
#undef FUSE_STEP

#pragma unroll
  for (int o = 8; o < 16; ++o) out[o] = fmaxf(out[o], 0.f);

  if (valid) {
    float4* r = (float4*)(result + (size_t)n * 16);
    r[0] = make_float4(out[0], out[1], out[2], out[3]);
    r[1] = make_float4(out[4], out[5], out[6], out[7]);
    r[2] = make_float4(out[8], out[9], out[10], out[11]);
    r[3] = make_float4(out[12], out[13], out[14], out[15]);
  } else {
#pragma unroll
    for (int o = 0; o < 16; ++o) out[o] = 0.f;
  }

#pragma unroll
  for (int o = 0; o < 16; ++o) {
    float s = out[o];
    float qq = out[o] * out[o];
#pragma unroll
    for (int m = 32; m >= 1; m >>= 1) {
      s += __shfl_xor(s, m, 64);
      qq += __shfl_xor(qq, m, 64);
    }
    if ((t & 63) == 0) {
      atomicAdd(&sstat[o], s);
      atomicAdd(&sstat[16 + o], qq);
    }
  }
  __syncthreads();
  if (t < 32) atomicAdd(&stats[t], sstat[t]);
}

// ---------------------------------------------------------------------------
__global__ void bn_coeffs(float* __restrict__ stats,
                          const float* __restrict__ gamma,
                          const float* __restrict__ beta) {
  int t = threadIdx.x;
  if (t < 16) {
    float mean = stats[t] * (1.0f / Nn);
    float var  = stats[16 + t] * (1.0f / Nn) - mean * mean;
    float sc   = gamma[t] * rsqrtf(var + 1e-5f);
    stats[32 + t] = sc;
    stats[48 + t] = beta[t] - mean * sc;
  }
}

__global__ __launch_bounds__(256) void bn_apply(
    float* __restrict__ result, const float* __restrict__ stats) {
  int idx = blockIdx.x * 256 + threadIdx.x;          // over Nn*4
  if (idx >= Nn * 4) return;
  int c = (idx & 3) * 4;
  float4 r = ((const float4*)result)[idx];
  float4 o;
  o.x = r.x * stats[32 + c + 0] + stats[48 + c + 0];
  o.y = r.y * stats[32 + c + 1] + stats[48 + c + 1];
  o.z = r.z * stats[32 + c + 2] + stats[48 + c + 2];
  o.w = r.w * stats[32 + c + 3] + stats[48 + c + 3];
  ((float4*)result)[idx] = o;
}

// ---------------------------------------------------------------------------
extern "C" void kernel_launch(void* const* d_in, const int* in_sizes, int n_in,
                              void* d_out, int out_size, void* d_ws, size_t ws_size,
                              hipStream_t stream) {
  const float* feat_a  = (const float*)d_in[0];
  const float* feat_b  = (const float*)d_in[1];
  const float* deg     = (const float*)d_in[2];
  const float* pm_vals = (const float*)d_in[3];
  const float* W_prev  = (const float*)d_in[4];
  const float* b_prev  = (const float*)d_in[5];
  const float* W_deg   = (const float*)d_in[6];
  const float* b_deg   = (const float*)d_in[7];
  const float* W_rad   = (const float*)d_in[8];
  const float* b_rad   = (const float*)d_in[9];
  const float* W_fuse  = (const float*)d_in[10];
  const float* b_fuse  = (const float*)d_in[11];
  const float* bn_g    = (const float*)d_in[12];
  const float* bn_b    = (const float*)d_in[13];
  const int*   src     = (const int*)d_in[14];
  const int*   dst     = (const int*)d_in[15];
  const int*   pm_rows = (const int*)d_in[16];
  const int*   pm_cols = (const int*)d_in[17];

  int* ws = (int*)d_ws;
  // Region A (Ee ints = 12.8MB): pm sort staging (per-phase), then csr_src.
  // Region B (2*NNZ ints = 51.2MB): binned pm, then binned edges, then z1..z4.
  int*   A    = ws;
  int*   B    = ws + (size_t)Ee;
  float* pm_y = (float*)(ws + (size_t)Ee + 2 * (size_t)NNZn);   // NF floats
  int*   T    = (int*)(pm_y + NF);
  int*   tot_e = T;                       // K
  int*   tot_p = T + K;                   // K
  float* stats = (float*)(T + 2 * K);     // 64
  int*   bs_e  = T + 2 * K + 64;          // K+1
  int*   cur_e = bs_e + K + 1;            // K
  int*   bs_p  = cur_e + K;               // K+1
  int*   cur_p = bs_p + K + 1;            // K
  int*   rp_e  = cur_p + K;               // Nn+1
  int*   rp_p  = rp_e + Nn + 1;           // Nn+1

  int2*  bp       = (int2*)B;
  int2*  dcsr     = (int2*)A;
  int*   binned_e = B;
  int*   csr_src  = A;
  float* z1 = (float*)B;
  float* z2 = z1 + (size_t)NF;
  float* z3 = z2 + (size_t)NF;
  float* z4 = z3 + (size_t)NF;
  float* result = (float*)d_out;

  // zero coarse totals + stats (contiguous)
  hipMemsetAsync(T, 0, (size_t)(2 * K + 64) * sizeof(int), stream);

  int cb_e = (Ee + CHUNK - 1) / CHUNK;     // 196
  int cb_p = (NNZn + CHUNK - 1) / CHUNK;   // 391
  count_kernel<<<cb_e, 256, 0, stream>>>(dst, Ee, tot_e);
  count_kernel<<<cb_p, 256, 0, stream>>>(pm_rows, NNZn, tot_p);
  scan_kernel<<<2, 1024, 0, stream>>>(tot_e, tot_p, bs_e, cur_e, bs_p, cur_p);

  // pm: coarse bin -> phased {bucket sort into A, consume into pm_y}
  bin_pm<<<cb_p, 256, 0, stream>>>(pm_rows, pm_cols, pm_vals, cur_p, bp);
  const int pb[6] = {0, 205, 410, 615, 820, 1024};
  for (int q = 0; q < 5; ++q) {
    int b0 = pb[q], b1 = pb[q + 1];
    sort_pm<<<b1 - b0, 256, 0, stream>>>(bp, bs_p, b0, dcsr, rp_p);
    int r0 = b0 * RPB;
    int r1 = (b1 * RPB < Nn) ? b1 * RPB : Nn;
    int nb = ((r1 - r0) * 4 + 255) / 256;
    pm_csr4<<<nb, 256, 0, stream>>>(feat_b, dcsr, rp_p, pm_y, r0, r1);
  }

  // edges: coarse bin into B[0..Ee) (bp dead), sort into A (staging dead)
  bin_edges<<<cb_e, 256, 0, stream>>>(dst, src, cur_e, binned_e);
  sort_edges<<<K, 256, 0, stream>>>(binned_e, bs_e, csr_src, rp_e);

  // hops (z buffers overwrite binned_e region, dead after sort_edges)
  int hop_blocks = (Nn * 4 + 255) / 256;   // 1563
  hop_csr4<<<hop_blocks, 256, 0, stream>>>(feat_a, z1, csr_src, rp_e);
  hop_csr4<<<hop_blocks, 256, 0, stream>>>(z1, z2, csr_src, rp_e);
  hop_csr4<<<hop_blocks, 256, 0, stream>>>(z2, z3, csr_src, rp_e);
  hop_csr4<<<hop_blocks, 256, 0, stream>>>(z3, z4, csr_src, rp_e);

  int fuse_blocks = (Nn + 255) / 256;
  fuse_kernel<<<fuse_blocks, 256, 0, stream>>>(
      feat_a, deg, z1, z2, z4, pm_y,
      W_prev, b_prev, W_deg, b_deg, W_rad, b_rad, W_fuse, b_fuse,
      result, stats);

  bn_coeffs<<<1, 64, 0, stream>>>(stats, bn_g, bn_b);

  int bn_blocks = (Nn * 4 + 255) / 256;
  bn_apply<<<bn_blocks, 256, 0, stream>>>(result, stats);
}

// Round 4
// 1135.737 us; speedup vs baseline: 2.2447x; 1.0107x over previous
//
#include <hip/hip_runtime.h>
#include <math.h>

#define Nn    100000
#define Ee    3200000
#define NNZn  6400000
#define NF    (Nn * 16)     // floats per node-feature buffer
#define K     256           // coarse row buckets (512B pm write runs)
#define RPB   391           // rows per bucket = ceil(Nn/K)
#define CHUNK 16384         // items per binning block

// ---------------------------------------------------------------------------
// Coarse count: per-block LDS histogram of key/RPB, one global atomic/bucket.
// ---------------------------------------------------------------------------
__global__ __launch_bounds__(256) void count_kernel(
    const int* __restrict__ keys, int n, int* __restrict__ tot) {
  __shared__ int h[K];
  int t = threadIdx.x;
  if (t < K) h[t] = 0;
  __syncthreads();
  int base = blockIdx.x * CHUNK;
  int end = min(base + CHUNK, n);
  for (int i = base + t; i < end; i += 256) atomicAdd(&h[keys[i] / RPB], 1);
  __syncthreads();
  if (t < K && h[t]) atomicAdd(&tot[t], h[t]);
}

// ---------------------------------------------------------------------------
// Exclusive scan of K bucket totals -> bucket_start + cursor. 2 blocks x K.
// ---------------------------------------------------------------------------
__global__ __launch_bounds__(K) void scan_kernel(
    const int* __restrict__ tot_e, const int* __restrict__ tot_p,
    int* __restrict__ bs_e, int* __restrict__ cur_e,
    int* __restrict__ bs_p, int* __restrict__ cur_p) {
  const int* tot = (blockIdx.x == 0) ? tot_e : tot_p;
  int* bs  = (blockIdx.x == 0) ? bs_e  : bs_p;
  int* cur = (blockIdx.x == 0) ? cur_e : cur_p;
  __shared__ int s[K];
  int t = threadIdx.x;
  s[t] = tot[t];
  __syncthreads();
  for (int off = 1; off < K; off <<= 1) {
    int v = (t >= off) ? s[t - off] : 0;
    __syncthreads();
    s[t] += v;
    __syncthreads();
  }
  int excl = t ? s[t - 1] : 0;
  bs[t] = excl;
  cur[t] = excl;
  if (t == K - 1) bs[K] = s[K - 1];
}

// ---------------------------------------------------------------------------
// Coarse bin edges: binned[pos] = (local_row<<17) | src.  Block-batched
// cursor reservation -> 256B contiguous write runs per (block,bucket).
// ---------------------------------------------------------------------------
__global__ __launch_bounds__(256) void bin_edges(
    const int* __restrict__ dst, const int* __restrict__ src,
    int* __restrict__ cur, int* __restrict__ binned) {
  __shared__ int h[K];
  int t = threadIdx.x;
  if (t < K) h[t] = 0;
  __syncthreads();
  int base = blockIdx.x * CHUNK;
  int end = min(base + CHUNK, Ee);
  for (int i = base + t; i < end; i += 256) atomicAdd(&h[dst[i] / RPB], 1);
  __syncthreads();
  if (t < K) {
    int c = h[t];
    h[t] = c ? atomicAdd(&cur[t], c) : 0;
  }
  __syncthreads();
  for (int i = base + t; i < end; i += 256) {
    int d = dst[i];
    int k = d / RPB;
    int lr = d - k * RPB;
    int pos = atomicAdd(&h[k], 1);
    binned[pos] = (lr << 17) | src[i];
  }
}

// ---------------------------------------------------------------------------
// Coarse bin pm: bp[pos] = { (local_row<<22)|col , bits(val) }.
// 512B write runs per (block,bucket).
// ---------------------------------------------------------------------------
__global__ __launch_bounds__(256) void bin_pm(
    const int* __restrict__ rows, const int* __restrict__ cols,
    const float* __restrict__ vals,
    int* __restrict__ cur, int2* __restrict__ bp) {
  __shared__ int h[K];
  int t = threadIdx.x;
  if (t < K) h[t] = 0;
  __syncthreads();
  int base = blockIdx.x * CHUNK;
  int end = min(base + CHUNK, NNZn);
  for (int i = base + t; i < end; i += 256) atomicAdd(&h[rows[i] / RPB], 1);
  __syncthreads();
  if (t < K) {
    int c = h[t];
    h[t] = c ? atomicAdd(&cur[t], c) : 0;
  }
  __syncthreads();
  for (int i = base + t; i < end; i += 256) {
    int r = rows[i];
    int k = r / RPB;
    int lr = r - k * RPB;
    int pos = atomicAdd(&h[k], 1);
    bp[pos] = make_int2((lr << 22) | cols[i], __float_as_int(vals[i]));
  }
}

// ---------------------------------------------------------------------------
// Per-bucket sort (edges): LDS 391-row hist + 512-wide scan, write row_ptr,
// scatter into contiguous CSR run [bs[b], bs[b+1]) (~50KB, L2-resident).
// ---------------------------------------------------------------------------
__global__ __launch_bounds__(1024) void sort_edges(
    const int* __restrict__ be, const int* __restrict__ bs,
    int* __restrict__ csr, int* __restrict__ rp) {
  __shared__ int hist[RPB];
  __shared__ int sc[512];
  int b = blockIdx.x, t = threadIdx.x;
  if (t < RPB) hist[t] = 0;
  __syncthreads();
  int s0 = bs[b], s1 = bs[b + 1];
  for (int i = s0 + t; i < s1; i += 1024)
    atomicAdd(&hist[be[i] >> 17], 1);
  __syncthreads();
  if (t < 512) sc[t] = (t < RPB) ? hist[t] : 0;
  __syncthreads();
  for (int off = 1; off < 512; off <<= 1) {
    int v = 0;
    if (t < 512 && t >= off) v = sc[t - off];
    __syncthreads();
    if (t < 512) sc[t] += v;
    __syncthreads();
  }
  int r0 = b * RPB;
  if (t < RPB) {
    int r = r0 + t;
    if (r < Nn) rp[r + 1] = s0 + sc[t];
    hist[t] = s0 + sc[t] - hist[t];  // exclusive start = cursor
  }
  if (b == 0 && t == 0) rp[0] = 0;
  __syncthreads();
  for (int i = s0 + t; i < s1; i += 1024) {
    int p = be[i];
    int pos = atomicAdd(&hist[p >> 17], 1);
    csr[pos] = p & 0x1FFFF;
  }
}

// ---------------------------------------------------------------------------
// Per-bucket sort (pm), phased: buckets [b0, b0+grid) scatter into the
// staging region with PHASE-LOCAL offsets (~200KB window per bucket).
// ---------------------------------------------------------------------------
__global__ __launch_bounds__(1024) void sort_pm(
    const int2* __restrict__ bpi, const int* __restrict__ bs, int b0,
    int2* __restrict__ dcsr, int* __restrict__ rp) {
  __shared__ int hist[RPB];
  __shared__ int sc[512];
  int b = b0 + blockIdx.x, t = threadIdx.x;
  if (t < RPB) hist[t] = 0;
  __syncthreads();
  int s0 = bs[b], s1 = bs[b + 1];
  int base = s0 - bs[b0];          // phase-local base
  for (int i = s0 + t; i < s1; i += 1024)
    atomicAdd(&hist[bpi[i].x >> 22], 1);
  __syncthreads();
  if (t < 512) sc[t] = (t < RPB) ? hist[t] : 0;
  __syncthreads();
  for (int off = 1; off < 512; off <<= 1) {
    int v = 0;
    if (t < 512 && t >= off) v = sc[t - off];
    __syncthreads();
    if (t < 512) sc[t] += v;
    __syncthreads();
  }
  int r0 = b * RPB;
  if (t < RPB) {
    int r = r0 + t;
    if (r < Nn) rp[r + 1] = base + sc[t];
    hist[t] = base + sc[t] - hist[t];  // phase-local exclusive cursor
  }
  if (b == b0 && t == 0) rp[r0] = 0;
  __syncthreads();
  for (int i = s0 + t; i < s1; i += 1024) {
    int2 e = bpi[i];
    int pos = atomicAdd(&hist[e.x >> 22], 1);
    dcsr[pos] = make_int2(e.x & 0x3FFFFF, e.y);
  }
}

// ---------------------------------------------------------------------------
// CSR hop, float4: 4 lanes per row, 8 float4 gathers in flight per lane.
// ---------------------------------------------------------------------------
__global__ __launch_bounds__(256) void hop_csr4(
    const float* __restrict__ zin, float* __restrict__ zout,
    const int* __restrict__ cs, const int* __restrict__ rp) {
  int gid = (blockIdx.x * 256 + threadIdx.x) >> 2;
  int q = (threadIdx.x & 3) * 4;
  if (gid >= Nn) return;
  int j = rp[gid], e = rp[gid + 1];
  float ax = 0.f, ay = 0.f, az = 0.f, aw = 0.f;
  for (; j + 8 <= e; j += 8) {
    int s0 = cs[j],     s1 = cs[j + 1], s2 = cs[j + 2], s3 = cs[j + 3];
    int s4 = cs[j + 4], s5 = cs[j + 5], s6 = cs[j + 6], s7 = cs[j + 7];
    float4 x0 = *(const float4*)(zin + (size_t)s0 * 16 + q);
    float4 x1 = *(const float4*)(zin + (size_t)s1 * 16 + q);
    float4 x2 = *(const float4*)(zin + (size_t)s2 * 16 + q);
    float4 x3 = *(const float4*)(zin + (size_t)s3 * 16 + q);
    float4 x4 = *(const float4*)(zin + (size_t)s4 * 16 + q);
    float4 x5 = *(const float4*)(zin + (size_t)s5 * 16 + q);
    float4 x6 = *(const float4*)(zin + (size_t)s6 * 16 + q);
    float4 x7 = *(const float4*)(zin + (size_t)s7 * 16 + q);
    ax += ((x0.x + x1.x) + (x2.x + x3.x)) + ((x4.x + x5.x) + (x6.x + x7.x));
    ay += ((x0.y + x1.y) + (x2.y + x3.y)) + ((x4.y + x5.y) + (x6.y + x7.y));
    az += ((x0.z + x1.z) + (x2.z + x3.z)) + ((x4.z + x5.z) + (x6.z + x7.z));
    aw += ((x0.w + x1.w) + (x2.w + x3.w)) + ((x4.w + x5.w) + (x6.w + x7.w));
  }
  for (; j < e; ++j) {
    float4 x = *(const float4*)(zin + (size_t)cs[j] * 16 + q);
    ax += x.x; ay += x.y; az += x.z; aw += x.w;
  }
  *(float4*)(zout + (size_t)gid * 16 + q) = make_float4(ax, ay, az, aw);
}

// ---------------------------------------------------------------------------
// CSR pm, float4, phased over row range [r0, r1).
// ---------------------------------------------------------------------------
__global__ __launch_bounds__(256) void pm_csr4(
    const float* __restrict__ fb, const int2* __restrict__ bp,
    const int* __restrict__ rp, float* __restrict__ pmy,
    int r0, int r1) {
  int gid = r0 + ((blockIdx.x * 256 + threadIdx.x) >> 2);
  int q = (threadIdx.x & 3) * 4;
  if (gid >= r1) return;
  int j = rp[gid], e = rp[gid + 1];
  float ax = 0.f, ay = 0.f, az = 0.f, aw = 0.f;
  for (; j + 8 <= e; j += 8) {
    int2 e0 = bp[j];     int2 e1 = bp[j + 1];
    int2 e2 = bp[j + 2]; int2 e3 = bp[j + 3];
    int2 e4 = bp[j + 4]; int2 e5 = bp[j + 5];
    int2 e6 = bp[j + 6]; int2 e7 = bp[j + 7];
    float4 x0 = *(const float4*)(fb + (size_t)e0.x * 16 + q);
    float4 x1 = *(const float4*)(fb + (size_t)e1.x * 16 + q);
    float4 x2 = *(const float4*)(fb + (size_t)e2.x * 16 + q);
    float4 x3 = *(const float4*)(fb + (size_t)e3.x * 16 + q);
    float4 x4 = *(const float4*)(fb + (size_t)e4.x * 16 + q);
    float4 x5 = *(const float4*)(fb + (size_t)e5.x * 16 + q);
    float4 x6 = *(const float4*)(fb + (size_t)e6.x * 16 + q);
    float4 x7 = *(const float4*)(fb + (size_t)e7.x * 16 + q);
    float v0 = __int_as_float(e0.y), v1 = __int_as_float(e1.y);
    float v2 = __int_as_float(e2.y), v3 = __int_as_float(e3.y);
    float v4 = __int_as_float(e4.y), v5 = __int_as_float(e5.y);
    float v6 = __int_as_float(e6.y), v7 = __int_as_float(e7.y);
    ax = fmaf(v0, x0.x, ax); ay = fmaf(v0, x0.y, ay);
    az = fmaf(v0, x0.z, az); aw = fmaf(v0, x0.w, aw);
    ax = fmaf(v1, x1.x, ax); ay = fmaf(v1, x1.y, ay);
    az = fmaf(v1, x1.z, az); aw = fmaf(v1, x1.w, aw);
    ax = fmaf(v2, x2.x, ax); ay = fmaf(v2, x2.y, ay);
    az = fmaf(v2, x2.z, az); aw = fmaf(v2, x2.w, aw);
    ax = fmaf(v3, x3.x, ax); ay = fmaf(v3, x3.y, ay);
    az = fmaf(v3, x3.z, az); aw = fmaf(v3, x3.w, aw);
    ax = fmaf(v4, x4.x, ax); ay = fmaf(v4, x4.y, ay);
    az = fmaf(v4, x4.z, az); aw = fmaf(v4, x4.w, aw);
    ax = fmaf(v5, x5.x, ax); ay = fmaf(v5, x5.y, ay);
    az = fmaf(v5, x5.z, az); aw = fmaf(v5, x5.w, aw);
    ax = fmaf(v6, x6.x, ax); ay = fmaf(v6, x6.y, ay);
    az = fmaf(v6, x6.z, az); aw = fmaf(v6, x6.w, aw);
    ax = fmaf(v7, x7.x, ax); ay = fmaf(v7, x7.y, ay);
    az = fmaf(v7, x7.z, az); aw = fmaf(v7, x7.w, aw);
  }
  for (; j < e; ++j) {
    int2 ee = bp[j];
    float4 x = *(const float4*)(fb + (size_t)ee.x * 16 + q);
    float v = __int_as_float(ee.y);
    ax = fmaf(v, x.x, ax); ay = fmaf(v, x.y, ay);
    az = fmaf(v, x.z, az); aw = fmaf(v, x.w, aw);
  }
  *(float4*)(pmy + (size_t)gid * 16 + q) = make_float4(ax, ay, az, aw);
}

// ---------------------------------------------------------------------------
// Fused per-node projections + ReLU(second half) + BN-stat reduction.
// (round-3 verified version: named float4 streaming, no scratch arrays)
// ---------------------------------------------------------------------------
__global__ __launch_bounds__(256) void fuse_kernel(
    const float* __restrict__ feat_a, const float* __restrict__ deg,
    const float* __restrict__ z1, const float* __restrict__ z2,
    const float* __restrict__ z4, const float* __restrict__ pmy,
    const float* __restrict__ Wprev, const float* __restrict__ bprev,
    const float* __restrict__ Wdeg,  const float* __restrict__ bdeg,
    const float* __restrict__ Wrad,  const float* __restrict__ brad,
    const float* __restrict__ Wfuse, const float* __restrict__ bfuse,
    float* __restrict__ result, float* __restrict__ stats) {
  __shared__ float sWp[256], sWd[256], sWr[768], sWf[256], sB[16];
  __shared__ float sstat[32];
  int t = threadIdx.x;
  sWp[t] = Wprev[t];
  sWd[t] = Wdeg[t];
  sWf[t] = Wfuse[t];
  for (int i = t; i < 768; i += 256) sWr[i] = Wrad[i];
  if (t < 32) sstat[t] = 0.f;
  if (t < 16)
    sB[t] = bprev[t] + bdeg[t] + brad[t] + brad[16 + t] + brad[32 + t] + bfuse[t];
  __syncthreads();

  int n = blockIdx.x * 256 + t;
  bool valid = n < Nn;
  int nc = valid ? n : (Nn - 1);   // clamp: loads always in-bounds

  float dg = deg[nc];
  float out[16];
#pragma unroll
  for (int o = 0; o < 16; ++o) out[o] = sB[o];

  const float4* pa = (const float4*)(feat_a + (size_t)nc * 16);
  const float4* p1 = (const float4*)(z1 + (size_t)nc * 16);
  const float4* p2 = (const float4*)(z2 + (size_t)nc * 16);
  const float4* p4 = (const float4*)(z4 + (size_t)nc * 16);
  const float4* pp = (const float4*)(pmy + (size_t)nc * 16);

#define FUSE_STEP(E, XA, X1, X2, X4, XP)                                  \
  {                                                                       \
    int i = c * 4 + (E);                                                  \
    float va = (XA);                                                      \
    float vd = dg * va;                                                   \
    float v1 = (X1), v2 = (X2), v4 = (X4), vp = (XP);                     \
    _Pragma("unroll")                                                     \
    for (int o = 0; o < 16; ++o) {                                        \
      float acc = out[o];                                                 \
      acc = fmaf(va, sWp[i * 16 + o], acc);                               \
      acc = fmaf(vd, sWd[i * 16 + o], acc);                               \
      acc = fmaf(v1, sWr[i * 16 + o], acc);                               \
      acc = fmaf(v2, sWr[256 + i * 16 + o], acc);                         \
      acc = fmaf(v4, sWr[512 + i * 16 + o], acc);                         \
      acc = fmaf(vp, sWf[i * 16 + o], acc);                               \
      out[o] = acc;                                                       \
    }                                                                     \
  }

#pragma unroll
  for (int c = 0; c < 4; ++c) {
    float4 xa = pa[c];
    float4 x1 = p1[c];
    float4 x2 = p2[c];
    float4 x4 = p4[c];
    float4 xp = pp[c];
    FUSE_STEP(0, xa.x, x1.x, x2.x, x4.x, xp.x)
    FUSE_STEP(1, xa.y, x1.y, x2.y, x4.y, xp.y)
    FUSE_STEP(2, xa.z, x1.z, x2.z, x4.z, xp.z)
    FUSE_STEP(3, xa.w, x1.w, x2.w, x4.w, xp.w)
  }
#undef FUSE_STEP

#pragma unroll
  for (int o = 8; o < 16; ++o) out[o] = fmaxf(out[o], 0.f);

  if (valid) {
    float4* r = (float4*)(result + (size_t)n * 16);
    r[0] = make_float4(out[0], out[1], out[2], out[3]);
    r[1] = make_float4(out[4], out[5], out[6], out[7]);
    r[2] = make_float4(out[8], out[9], out[10], out[11]);
    r[3] = make_float4(out[12], out[13], out[14], out[15]);
  } else {
#pragma unroll
    for (int o = 0; o < 16; ++o) out[o] = 0.f;
  }

#pragma unroll
  for (int o = 0; o < 16; ++o) {
    float s = out[o];
    float qq = out[o] * out[o];
#pragma unroll
    for (int m = 32; m >= 1; m >>= 1) {
      s += __shfl_xor(s, m, 64);
      qq += __shfl_xor(qq, m, 64);
    }
    if ((t & 63) == 0) {
      atomicAdd(&sstat[o], s);
      atomicAdd(&sstat[16 + o], qq);
    }
  }
  __syncthreads();
  if (t < 32) atomicAdd(&stats[t], sstat[t]);
}

// ---------------------------------------------------------------------------
__global__ void bn_coeffs(float* __restrict__ stats,
                          const float* __restrict__ gamma,
                          const float* __restrict__ beta) {
  int t = threadIdx.x;
  if (t < 16) {
    float mean = stats[t] * (1.0f / Nn);
    float var  = stats[16 + t] * (1.0f / Nn) - mean * mean;
    float sc   = gamma[t] * rsqrtf(var + 1e-5f);
    stats[32 + t] = sc;
    stats[48 + t] = beta[t] - mean * sc;
  }
}

__global__ __launch_bounds__(256) void bn_apply(
    float* __restrict__ result, const float* __restrict__ stats) {
  int idx = blockIdx.x * 256 + threadIdx.x;          // over Nn*4
  if (idx >= Nn * 4) return;
  int c = (idx & 3) * 4;
  float4 r = ((const float4*)result)[idx];
  float4 o;
  o.x = r.x * stats[32 + c + 0] + stats[48 + c + 0];
  o.y = r.y * stats[32 + c + 1] + stats[48 + c + 1];
  o.z = r.z * stats[32 + c + 2] + stats[48 + c + 2];
  o.w = r.w * stats[32 + c + 3] + stats[48 + c + 3];
  ((float4*)result)[idx] = o;
}

// ---------------------------------------------------------------------------
extern "C" void kernel_launch(void* const* d_in, const int* in_sizes, int n_in,
                              void* d_out, int out_size, void* d_ws, size_t ws_size,
                              hipStream_t stream) {
  const float* feat_a  = (const float*)d_in[0];
  const float* feat_b  = (const float*)d_in[1];
  const float* deg     = (const float*)d_in[2];
  const float* pm_vals = (const float*)d_in[3];
  const float* W_prev  = (const float*)d_in[4];
  const float* b_prev  = (const float*)d_in[5];
  const float* W_deg   = (const float*)d_in[6];
  const float* b_deg   = (const float*)d_in[7];
  const float* W_rad   = (const float*)d_in[8];
  const float* b_rad   = (const float*)d_in[9];
  const float* W_fuse  = (const float*)d_in[10];
  const float* b_fuse  = (const float*)d_in[11];
  const float* bn_g    = (const float*)d_in[12];
  const float* bn_b    = (const float*)d_in[13];
  const int*   src     = (const int*)d_in[14];
  const int*   dst     = (const int*)d_in[15];
  const int*   pm_rows = (const int*)d_in[16];
  const int*   pm_cols = (const int*)d_in[17];

  int* ws = (int*)d_ws;
  // Region A (Ee ints = 12.8MB): pm sort staging (per-phase), then csr_src.
  // Region B (2*NNZ ints = 51.2MB): binned pm, then binned edges, then z1..z4.
  int*   A    = ws;
  int*   B    = ws + (size_t)Ee;
  float* pm_y = (float*)(ws + (size_t)Ee + 2 * (size_t)NNZn);   // NF floats
  int*   T    = (int*)(pm_y + NF);
  int*   tot_e = T;                       // K
  int*   tot_p = T + K;                   // K
  float* stats = (float*)(T + 2 * K);     // 64
  int*   bs_e  = T + 2 * K + 64;          // K+1
  int*   cur_e = bs_e + K + 1;            // K
  int*   bs_p  = cur_e + K;               // K+1
  int*   cur_p = bs_p + K + 1;            // K
  int*   rp_e  = cur_p + K;               // Nn+1
  int*   rp_p  = rp_e + Nn + 1;           // Nn+1

  int2*  bp       = (int2*)B;
  int2*  dcsr     = (int2*)A;
  int*   binned_e = B;
  int*   csr_src  = A;
  float* z1 = (float*)B;
  float* z2 = z1 + (size_t)NF;
  float* z3 = z2 + (size_t)NF;
  float* z4 = z3 + (size_t)NF;
  float* result = (float*)d_out;

  // zero coarse totals + stats (contiguous)
  hipMemsetAsync(T, 0, (size_t)(2 * K + 64) * sizeof(int), stream);

  int cb_e = (Ee + CHUNK - 1) / CHUNK;     // 196
  int cb_p = (NNZn + CHUNK - 1) / CHUNK;   // 391
  count_kernel<<<cb_e, 256, 0, stream>>>(dst, Ee, tot_e);
  count_kernel<<<cb_p, 256, 0, stream>>>(pm_rows, NNZn, tot_p);
  scan_kernel<<<2, K, 0, stream>>>(tot_e, tot_p, bs_e, cur_e, bs_p, cur_p);

  // pm: coarse bin -> phased {bucket sort into A, consume into pm_y}
  bin_pm<<<cb_p, 256, 0, stream>>>(pm_rows, pm_cols, pm_vals, cur_p, bp);
  const int pb[6] = {0, 52, 103, 154, 205, 256};
  for (int q = 0; q < 5; ++q) {
    int b0 = pb[q], b1 = pb[q + 1];
    sort_pm<<<b1 - b0, 1024, 0, stream>>>(bp, bs_p, b0, dcsr, rp_p);
    int r0 = b0 * RPB;
    int r1 = (b1 * RPB < Nn) ? b1 * RPB : Nn;
    int nb = ((r1 - r0) * 4 + 255) / 256;
    pm_csr4<<<nb, 256, 0, stream>>>(feat_b, dcsr, rp_p, pm_y, r0, r1);
  }

  // edges: coarse bin into B[0..Ee) (bp dead), sort into A (staging dead)
  bin_edges<<<cb_e, 256, 0, stream>>>(dst, src, cur_e, binned_e);
  sort_edges<<<K, 1024, 0, stream>>>(binned_e, bs_e, csr_src, rp_e);

  // hops (z buffers overwrite binned_e region, dead after sort_edges)
  int hop_blocks = (Nn * 4 + 255) / 256;   // 1563
  hop_csr4<<<hop_blocks, 256, 0, stream>>>(feat_a, z1, csr_src, rp_e);
  hop_csr4<<<hop_blocks, 256, 0, stream>>>(z1, z2, csr_src, rp_e);
  hop_csr4<<<hop_blocks, 256, 0, stream>>>(z2, z3, csr_src, rp_e);
  hop_csr4<<<hop_blocks, 256, 0, stream>>>(z3, z4, csr_src, rp_e);

  int fuse_blocks = (Nn + 255) / 256;
  fuse_kernel<<<fuse_blocks, 256, 0, stream>>>(
      feat_a, deg, z1, z2, z4, pm_y,
      W_prev, b_prev, W_deg, b_deg, W_rad, b_rad, W_fuse, b_fuse,
      result, stats);

  bn_coeffs<<<1, 64, 0, stream>>>(stats, bn_g, bn_b);

  int bn_blocks = (Nn * 4 + 255) / 256;
  bn_apply<<<bn_blocks, 256, 0, stream>>>(result, stats);
}